// Round 4
// baseline (396.508 us; speedup 1.0000x reference)
//
#include <hip/hip_runtime.h>
#include <math.h>

#define NB     32
#define FH     11
#define FW     20
#define CIN    512
#define CMID   1024
#define NANG   17
#define NPREDD 77
#define NEDGE  42
#define NPROPP 714
#define NOFF   72
#define NCLS   34
#define NREGR  1241
#define N2PAD  1280
#define MTOT   1344      // NB * NEDGE
#define NSTRIPSF 71.0f

typedef unsigned long long u64;

// ---------------- gather edge pixels: A0[m][c], m = b*42+e ----------------
__global__ __launch_bounds__(256) void k_gather(const float* __restrict__ feat,
                                                float* __restrict__ A0)
{
    int idx = blockIdx.x * 256 + threadIdx.x;    // exactly MTOT*CIN = 688128
    int m = idx >> 9, c = idx & 511;
    int b = m / NEDGE, e = m - b * NEDGE;
    int h, w;
    if (e < FH)          { h = e;      w = 0;      }
    else if (e < 2 * FH) { h = e - FH; w = FW - 1; }
    else                 { h = FH - 1; w = e - 2 * FH; }
    A0[idx] = feat[((size_t)(b * CIN + c) * FH + h) * FW + w];
}

__device__ inline void st8(float (*S)[68], int kc, int r, float4 a, float4 b)
{
    S[kc + 0][r] = a.x; S[kc + 1][r] = a.y; S[kc + 2][r] = a.z; S[kc + 3][r] = a.w;
    S[kc + 4][r] = b.x; S[kc + 5][r] = b.y; S[kc + 6][r] = b.z; S[kc + 7][r] = b.w;
}

// ---- GEMM1: C1[1344][1024] = A0[1344][512] * Wconv[1024][512]^T + b ----
// BK=32, double-buffered LDS, register prefetch of next tile. Per-element
// accumulation is ascending-k single chain -> bit-identical to prior rounds.
__global__ __launch_bounds__(256, 4) void k_gemm1(const float* __restrict__ A,
                                                  const float* __restrict__ W,
                                                  const float* __restrict__ bias,
                                                  float* __restrict__ C)
{
    __shared__ __align__(16) float As[2][32][68];
    __shared__ __align__(16) float Bs[2][32][68];
    const int K = CIN;
    int tid = threadIdx.x;
    int m0 = blockIdx.y * 64, n0 = blockIdx.x * 64;
    int tn = tid & 15, tm = tid >> 4;
    int r = tid >> 2, kc = (tid & 3) << 3;
    const float* Ap = A + (size_t)(m0 + r) * K + kc;
    const float* Wp = W + (size_t)(n0 + r) * K + kc;

    float4 pa0 = *(const float4*)(Ap);
    float4 pa1 = *(const float4*)(Ap + 4);
    float4 pb0 = *(const float4*)(Wp);
    float4 pb1 = *(const float4*)(Wp + 4);
    st8(As[0], kc, r, pa0, pa1);
    st8(Bs[0], kc, r, pb0, pb1);

    float acc[4][4];
#pragma unroll
    for (int i = 0; i < 4; ++i)
#pragma unroll
        for (int j = 0; j < 4; ++j) acc[i][j] = 0.f;

    int buf = 0;
    for (int k0 = 0; k0 < K; k0 += 32, buf ^= 1) {
        __syncthreads();
        bool more = (k0 + 32) < K;
        if (more) {
            pa0 = *(const float4*)(Ap + k0 + 32);
            pa1 = *(const float4*)(Ap + k0 + 36);
            pb0 = *(const float4*)(Wp + k0 + 32);
            pb1 = *(const float4*)(Wp + k0 + 36);
        }
#pragma unroll
        for (int kk = 0; kk < 32; ++kk) {
            float4 a = *(const float4*)&As[buf][kk][tm << 2];
            float4 b = *(const float4*)&Bs[buf][kk][tn << 2];
            float ar[4] = {a.x, a.y, a.z, a.w};
            float br[4] = {b.x, b.y, b.z, b.w};
#pragma unroll
            for (int i = 0; i < 4; ++i)
#pragma unroll
                for (int j = 0; j < 4; ++j)
                    acc[i][j] = fmaf(ar[i], br[j], acc[i][j]);
        }
        if (more) {
            st8(As[buf ^ 1], kc, r, pa0, pa1);
            st8(Bs[buf ^ 1], kc, r, pb0, pb1);
        }
    }
    float bb[4];
#pragma unroll
    for (int j = 0; j < 4; ++j) bb[j] = bias[n0 + (tn << 2) + j];
#pragma unroll
    for (int i = 0; i < 4; ++i) {
        float4 o;
        o.x = acc[i][0] + bb[0];
        o.y = acc[i][1] + bb[1];
        o.z = acc[i][2] + bb[2];
        o.w = acc[i][3] + bb[3];
        *(float4*)(C + (size_t)(m0 + (tm << 2) + i) * CMID + n0 + (tn << 2)) = o;
    }
}

// ---- GEMM2: C2[1344][1280] = C1 * [Wcls;Wreg;0]^T + [bcls;breg;0] ----
__global__ __launch_bounds__(256, 4) void k_gemm2(const float* __restrict__ A,
                                                  const float* __restrict__ Wcls,
                                                  const float* __restrict__ bcls,
                                                  const float* __restrict__ Wreg,
                                                  const float* __restrict__ breg,
                                                  float* __restrict__ C)
{
    __shared__ __align__(16) float As[2][32][68];
    __shared__ __align__(16) float Bs[2][32][68];
    const int K = CMID;
    int tid = threadIdx.x;
    int m0 = blockIdx.y * 64, n0 = blockIdx.x * 64;
    int tn = tid & 15, tm = tid >> 4;
    int r = tid >> 2, kc = (tid & 3) << 3;
    const float* Ap = A + (size_t)(m0 + r) * K + kc;
    int nrow = n0 + r;
    const float* Wrow = Wcls;
    bool wv = true;
    if (nrow < NCLS)              Wrow = Wcls + (size_t)nrow * K + kc;
    else if (nrow < NCLS + NREGR) Wrow = Wreg + (size_t)(nrow - NCLS) * K + kc;
    else                          wv = false;
    const float4 z4 = make_float4(0.f, 0.f, 0.f, 0.f);

    float4 pa0 = *(const float4*)(Ap);
    float4 pa1 = *(const float4*)(Ap + 4);
    float4 pb0 = wv ? *(const float4*)(Wrow)     : z4;
    float4 pb1 = wv ? *(const float4*)(Wrow + 4) : z4;
    st8(As[0], kc, r, pa0, pa1);
    st8(Bs[0], kc, r, pb0, pb1);

    float acc[4][4];
#pragma unroll
    for (int i = 0; i < 4; ++i)
#pragma unroll
        for (int j = 0; j < 4; ++j) acc[i][j] = 0.f;

    int buf = 0;
    for (int k0 = 0; k0 < K; k0 += 32, buf ^= 1) {
        __syncthreads();
        bool more = (k0 + 32) < K;
        if (more) {
            pa0 = *(const float4*)(Ap + k0 + 32);
            pa1 = *(const float4*)(Ap + k0 + 36);
            pb0 = wv ? *(const float4*)(Wrow + k0 + 32) : z4;
            pb1 = wv ? *(const float4*)(Wrow + k0 + 36) : z4;
        }
#pragma unroll
        for (int kk = 0; kk < 32; ++kk) {
            float4 a = *(const float4*)&As[buf][kk][tm << 2];
            float4 b = *(const float4*)&Bs[buf][kk][tn << 2];
            float ar[4] = {a.x, a.y, a.z, a.w};
            float br[4] = {b.x, b.y, b.z, b.w};
#pragma unroll
            for (int i = 0; i < 4; ++i)
#pragma unroll
                for (int j = 0; j < 4; ++j)
                    acc[i][j] = fmaf(ar[i], br[j], acc[i][j]);
        }
        if (more) {
            st8(As[buf ^ 1], kc, r, pa0, pa1);
            st8(Bs[buf ^ 1], kc, r, pb0, pb1);
        }
    }
    float bb[4];
#pragma unroll
    for (int j = 0; j < 4; ++j) {
        int n = n0 + (tn << 2) + j;
        bb[j] = (n < NCLS) ? bcls[n] : ((n < NCLS + NREGR) ? breg[n - NCLS] : 0.f);
    }
#pragma unroll
    for (int i = 0; i < 4; ++i) {
        float4 o;
        o.x = acc[i][0] + bb[0];
        o.y = acc[i][1] + bb[1];
        o.z = acc[i][2] + bb[2];
        o.w = acc[i][3] + bb[3];
        *(float4*)(C + (size_t)(m0 + (tm << 2) + i) * N2PAD + n0 + (tn << 2)) = o;
    }
}

// ---------------- assemble proposals + scores + start/end + xsel ----------------
__global__ __launch_bounds__(256) void k_assemble(const float* __restrict__ C2,
                                                  const float* __restrict__ AD,
                                                  float* __restrict__ outP,
                                                  float* __restrict__ outS,
                                                  float* __restrict__ startv,
                                                  float* __restrict__ endv,
                                                  float* __restrict__ xsel)
{
    int mb = blockIdx.x;                 // 0..1343
    int b = mb / NEDGE, e = mb - b * NEDGE;
    const float* c2 = C2 + (size_t)mb * N2PAD;
    int tid = threadIdx.x;
    for (int idx = tid; idx < NANG * NPREDD; idx += 256) {
        int a = idx / NPREDD, p = idx - a * NPREDD;
        int prop = e * NANG + a;
        float v;
        if (p < 2) v = c2[a * 2 + p];
        else {
            v = AD[prop * NPREDD + p];
            if (p >= 4) v += c2[NCLS + a * 73 + (p - 4)];
        }
        outP[((size_t)b * NPROPP + prop) * NPREDD + p] = v;
    }
    if (tid < NANG) {
        int a = tid, prop = e * NANG + a;
        float c0 = c2[2 * a], c1 = c2[2 * a + 1];
        float mx = fmaxf(c0, c1);
        float e0 = expf(c0 - mx), e1 = expf(c1 - mx);
        outS[b * NPROPP + prop] = e1 / (e0 + e1);
        float p2 = AD[prop * NPREDD + 2];
        float p4 = AD[prop * NPREDD + 4] + c2[NCLS + a * 73];
        float st = fminf(fmaxf(rintf(p2 * NSTRIPSF), 0.0f), NSTRIPSF);  // round half-to-even
        float en = fminf(fmaxf(st + p4 - 1.0f, 0.0f), NSTRIPSF);
        startv[b * 720 + prop] = st;
        endv[b * 720 + prop] = en;
        int ksi = (int)st;
        // bit-identical to outP[..][5+ksi]
        xsel[b * 720 + prop] = AD[prop * NPREDD + 5 + ksi] + c2[NCLS + a * 73 + ksi + 1];
    }
}

// ---------------- per-batch stable descending rank sort ----------------
__global__ __launch_bounds__(256) void k_sort(const float* __restrict__ scores,
                                              int* __restrict__ order)
{
    int b = blockIdx.x, tid = threadIdx.x;
    __shared__ float s[NPROPP];
    for (int i = tid; i < NPROPP; i += 256) s[i] = scores[b * NPROPP + i];
    __syncthreads();
    for (int i = tid; i < NPROPP; i += 256) {
        float si = s[i];
        int r = 0;
        for (int j = 0; j < NPROPP; ++j) {
            float sj = s[j];
            r += (sj > si) || (sj == si && j < i);
        }
        order[b * 720 + r] = i;
    }
}

// ---------------- suppression matrix, 64x64 tiles, xsel fast path ----------------
// With integer starts: nonempty integer range needs e >= s; dominant case is
// same-start single-strip k == start (use cached xsel); e<s with cnt>0 => dist=0
// => suppress; multi-strip / cross-start overlap is vanishingly rare -> global.
__global__ __launch_bounds__(256) void k_supmat(const float* __restrict__ outP,
                                                const float* __restrict__ startv,
                                                const float* __restrict__ endv,
                                                const float* __restrict__ xsel,
                                                const int* __restrict__ order,
                                                u64* __restrict__ sup)
{
    int jt = blockIdx.x, it = blockIdx.y, b = blockIdx.z;
    int i0 = it * 64, j0 = jt * 64;
    int tid = threadIdx.x;
    if (j0 + 63 < i0) {                  // strictly below diagonal: zero words
        if (tid < 64) {
            int il = i0 + tid;
            if (il < NPROPP) sup[((size_t)b * NPROPP + il) * 12 + jt] = 0ull;
        }
        return;
    }
    __shared__ float SI[64], EI[64], XI[64];
    __shared__ float SJ[64], EJ[64], XJ[64];
    __shared__ int   OI[64], OJ[64];
    if (tid < 128) {
        int side = tid >> 6, q = tid & 63;
        int pos = (side ? j0 : i0) + q;
        int o = (pos < NPROPP) ? order[b * 720 + pos] : -1;
        float st = (o >= 0) ? startv[b * 720 + o] : 0.f;
        float en = (o >= 0) ? endv[b * 720 + o] : -2.f;   // cnt<=-1 -> never suppress
        float xv = (o >= 0) ? xsel[b * 720 + o] : 0.f;
        if (!side) { SI[q] = st; EI[q] = en; XI[q] = xv; OI[q] = o; }
        else       { SJ[q] = st; EJ[q] = en; XJ[q] = xv; OJ[q] = o; }
    }
    __syncthreads();
    int lane = tid & 63, w = tid >> 6;
    int j = j0 + lane;
    float sj = SJ[lane], ej = EJ[lane], xj = XJ[lane];
    const float* basexs = outP + (size_t)b * NPROPP * NPREDD + 5;
#pragma unroll 1
    for (int rep = 0; rep < 16; ++rep) {
        int iloc = w * 16 + rep;
        int il = i0 + iloc;
        float si = SI[iloc], ei = EI[iloc];
        float s = fmaxf(si, sj), e = fminf(ei, ej);
        float cnt = e - s + 1.0f;
        bool sp = false;
        if (cnt > 0.f) {
            if (e < s) {
                sp = true;                               // empty range: dist = 0
            } else {
                int ks = (int)s, ke = (int)e;
                if (si == sj && ke == ks) {
                    sp = (fabsf(XI[iloc] - xj) / fmaxf(cnt, 1.0f)) < 15.0f;
                } else {                                  // rare general case
                    const float* xi  = basexs + (size_t)OI[iloc] * NPREDD;
                    const float* xjp = basexs + (size_t)OJ[lane] * NPREDD;
                    float sum = 0.f;
                    for (int k = ks; k <= ke; ++k)
                        sum += fabsf(xi[k] - xjp[k]);
                    sp = (sum / fmaxf(cnt, 1.0f)) < 15.0f;
                }
            }
        }
        bool valid = (il < NPROPP) && (j < NPROPP) && (j > il);
        u64 msk = __ballot(valid && sp);
        if (lane == 0 && il < NPROPP)
            sup[((size_t)b * NPROPP + il) * 12 + jt] = msk;
    }
}

// ---------------- sequential NMS scan (per batch, 1 wave) ----------------
__global__ __launch_bounds__(64) void k_scan(const u64* __restrict__ sup,
                                             const int* __restrict__ order,
                                             float* __restrict__ keep_out)
{
    int b = blockIdx.x, lane = threadIdx.x;
    __shared__ float keepv[NPROPP];
    __shared__ int ord[NPROPP];
    for (int x = lane; x < NPROPP; x += 64) { keepv[x] = 0.f; ord[x] = order[b * 720 + x]; }
    __syncthreads();
    const u64* base = sup + (size_t)b * NPROPP * 12;

    u64 S[12];
#pragma unroll
    for (int t = 0; t < 12; ++t) S[t] = 0ull;

    u64 cur[12], nxt[12];
    {
        int r = lane;
#pragma unroll
        for (int t = 0; t < 12; ++t)
            cur[t] = (r < NPROPP) ? base[(size_t)r * 12 + t] : 0ull;
    }

    for (int c = 0; c < 12; ++c) {
        if (c < 11) {
            int r = (c + 1) * 64 + lane;
#pragma unroll
            for (int t = 0; t < 12; ++t) {
                int w = c + 1 + t;
                nxt[t] = (r < NPROPP && w < 12) ? base[(size_t)r * 12 + w] : 0ull;
            }
        }
        int imax = NPROPP - c * 64; if (imax > 64) imax = 64;
        u64 keepbits = 0ull;
        for (int ib = 0; ib < imax; ++ib) {
            bool keep = ((S[0] >> ib) & 1ull) == 0ull;   // uniform
            if (keep) {
                keepbits |= (1ull << ib);
#pragma unroll
                for (int t = 0; t < 12; ++t) {
                    unsigned rlo = (unsigned)__builtin_amdgcn_readlane((int)(unsigned)cur[t], ib);
                    unsigned rhi = (unsigned)__builtin_amdgcn_readlane((int)(cur[t] >> 32), ib);
                    S[t] |= ((u64)rhi << 32) | (u64)rlo;
                }
            }
        }
        if (lane < imax)
            keepv[ord[c * 64 + lane]] = ((keepbits >> lane) & 1ull) ? 1.f : 0.f;
#pragma unroll
        for (int t = 0; t < 11; ++t) S[t] = S[t + 1];
        S[11] = 0ull;
#pragma unroll
        for (int t = 0; t < 12; ++t) cur[t] = nxt[t];
    }
    __syncthreads();
    for (int x = lane; x < NPROPP; x += 64) keep_out[b * NPROPP + x] = keepv[x];
}

extern "C" void kernel_launch(void* const* d_in, const int* in_sizes, int n_in,
                              void* d_out, int out_size, void* d_ws, size_t ws_size,
                              hipStream_t stream)
{
    const float* feat  = (const float*)d_in[0];
    const float* Wconv = (const float*)d_in[1];
    const float* bconv = (const float*)d_in[2];
    const float* Wcls  = (const float*)d_in[3];
    const float* bcls  = (const float*)d_in[4];
    const float* Wreg  = (const float*)d_in[5];
    const float* breg  = (const float*)d_in[6];
    const float* AD    = (const float*)d_in[8];   // anchors_anchor_dim (714,77)

    float* out  = (float*)d_out;
    float* outP = out;                                     // proposals 32*714*77
    float* outK = out + (size_t)NB * NPROPP * NPREDD;      // keep mask  32*714
    float* outS = outK + (size_t)NB * NPROPP;              // scores     32*714

    float* ws = (float*)d_ws;
    float* A0 = ws;                   // [0, 688128)         dead after gemm1
    float* C1 = ws + 688128;          // [688128, 2064384)   dead after gemm2
    float* C2 = ws + 2064384;         // [2064384, 3784704)
    // reuse A0 region (dead by the time these are written):
    float* startv = ws;                                    // 32*720 floats
    float* endv   = ws + 23040;                            // 32*720 floats
    int*   order  = (int*)(ws + 46080);                    // 32*720 ints
    u64*   sup    = (u64*)(ws + 69120);                    // 32*714*12 u64, ends @617472
    float* xsel   = ws + 617472;                           // 32*720 floats, ends @640512

    k_gather  <<<dim3(2688),        dim3(256), 0, stream>>>(feat, A0);
    k_gemm1   <<<dim3(16, 21),      dim3(256), 0, stream>>>(A0, Wconv, bconv, C1);
    k_gemm2   <<<dim3(20, 21),      dim3(256), 0, stream>>>(C1, Wcls, bcls, Wreg, breg, C2);
    k_assemble<<<dim3(MTOT),        dim3(256), 0, stream>>>(C2, AD, outP, outS, startv, endv, xsel);
    k_sort    <<<dim3(NB),          dim3(256), 0, stream>>>(outS, order);
    k_supmat  <<<dim3(12, 12, NB),  dim3(256), 0, stream>>>(outP, startv, endv, xsel, order, sup);
    k_scan    <<<dim3(NB),          dim3(64),  0, stream>>>(sup, order, outK);
}

// Round 5
// 301.619 us; speedup vs baseline: 1.3146x; 1.3146x over previous
//
#include <hip/hip_runtime.h>
#include <math.h>

#define NB     32
#define FH     11
#define FW     20
#define CIN    512
#define CMID   1024
#define NANG   17
#define NPREDD 77
#define NEDGE  42
#define NPROPP 714
#define NOFF   72
#define NCLS   34
#define NREGR  1241
#define N2PAD  1280
#define MTOT   1344      // NB * NEDGE
#define NSTRIPSF 71.0f

typedef unsigned long long u64;

// ---------------- gather edge pixels: A0[m][c], m = b*42+e ----------------
__global__ __launch_bounds__(256) void k_gather(const float* __restrict__ feat,
                                                float* __restrict__ A0)
{
    int idx = blockIdx.x * 256 + threadIdx.x;    // exactly MTOT*CIN = 688128
    int m = idx >> 9, c = idx & 511;
    int b = m / NEDGE, e = m - b * NEDGE;
    int h, w;
    if (e < FH)          { h = e;      w = 0;      }
    else if (e < 2 * FH) { h = e - FH; w = FW - 1; }
    else                 { h = FH - 1; w = e - 2 * FH; }
    A0[idx] = feat[((size_t)(b * CIN + c) * FH + h) * FW + w];
}

// ---- GEMM1: C1[1344][1024] = A0[1344][512] * Wconv[1024][512]^T + b ----
// 512 threads: waves 0-3 accumulate k in [0,K/2), waves 4-7 k in [K/2,K),
// each half running the proven R2 single-buffer BK=16 loop on its own LDS.
// Final C = (low + high) + bias, deterministic fixed order.
__global__ __launch_bounds__(512) void k_gemm1(const float* __restrict__ A,
                                               const float* __restrict__ W,
                                               const float* __restrict__ bias,
                                               float* __restrict__ C)
{
    __shared__ __align__(16) float As[2][16][68];
    __shared__ __align__(16) float Bs[2][16][68];
    __shared__ __align__(16) float Pr[64][68];
    const int K = CIN, K2 = CIN / 2;
    int tid = threadIdx.x;
    int half = tid >> 8, t = tid & 255;
    int m0 = blockIdx.y * 64, n0 = blockIdx.x * 64;
    int tn = t & 15, tm = t >> 4;
    int lr = t >> 2, lc = (t & 3) << 2;
    const float* Ap = A + (size_t)(m0 + lr) * K + half * K2 + lc;
    const float* Wp = W + (size_t)(n0 + lr) * K + half * K2 + lc;
    float acc[4][4];
#pragma unroll
    for (int i = 0; i < 4; ++i)
#pragma unroll
        for (int j = 0; j < 4; ++j) acc[i][j] = 0.f;

    for (int k0 = 0; k0 < K2; k0 += 16) {
        float4 av = *(const float4*)(Ap + k0);
        float4 wv = *(const float4*)(Wp + k0);
        As[half][lc + 0][lr] = av.x; As[half][lc + 1][lr] = av.y;
        As[half][lc + 2][lr] = av.z; As[half][lc + 3][lr] = av.w;
        Bs[half][lc + 0][lr] = wv.x; Bs[half][lc + 1][lr] = wv.y;
        Bs[half][lc + 2][lr] = wv.z; Bs[half][lc + 3][lr] = wv.w;
        __syncthreads();
#pragma unroll
        for (int kk = 0; kk < 16; ++kk) {
            float4 a = *(const float4*)&As[half][kk][tm << 2];
            float4 b = *(const float4*)&Bs[half][kk][tn << 2];
            float ar[4] = {a.x, a.y, a.z, a.w};
            float br[4] = {b.x, b.y, b.z, b.w};
#pragma unroll
            for (int i = 0; i < 4; ++i)
#pragma unroll
                for (int j = 0; j < 4; ++j)
                    acc[i][j] = fmaf(ar[i], br[j], acc[i][j]);
        }
        __syncthreads();
    }
    if (half == 1) {
#pragma unroll
        for (int i = 0; i < 4; ++i)
            *(float4*)&Pr[(tm << 2) + i][tn << 2] =
                make_float4(acc[i][0], acc[i][1], acc[i][2], acc[i][3]);
    }
    __syncthreads();
    if (half == 0) {
        float bb[4];
#pragma unroll
        for (int j = 0; j < 4; ++j) bb[j] = bias[n0 + (tn << 2) + j];
#pragma unroll
        for (int i = 0; i < 4; ++i) {
            float4 p = *(const float4*)&Pr[(tm << 2) + i][tn << 2];
            float4 o;
            o.x = (acc[i][0] + p.x) + bb[0];
            o.y = (acc[i][1] + p.y) + bb[1];
            o.z = (acc[i][2] + p.z) + bb[2];
            o.w = (acc[i][3] + p.w) + bb[3];
            *(float4*)(C + (size_t)(m0 + (tm << 2) + i) * CMID + n0 + (tn << 2)) = o;
        }
    }
}

// ---- GEMM2: C2[1344][1280] = C1 * [Wcls;Wreg;0]^T + [bcls;breg;0] ----
__global__ __launch_bounds__(512) void k_gemm2(const float* __restrict__ A,
                                               const float* __restrict__ Wcls,
                                               const float* __restrict__ bcls,
                                               const float* __restrict__ Wreg,
                                               const float* __restrict__ breg,
                                               float* __restrict__ C)
{
    __shared__ __align__(16) float As[2][16][68];
    __shared__ __align__(16) float Bs[2][16][68];
    __shared__ __align__(16) float Pr[64][68];
    const int K = CMID, K2 = CMID / 2;
    int tid = threadIdx.x;
    int half = tid >> 8, t = tid & 255;
    int m0 = blockIdx.y * 64, n0 = blockIdx.x * 64;
    int tn = t & 15, tm = t >> 4;
    int lr = t >> 2, lc = (t & 3) << 2;
    const float* Ap = A + (size_t)(m0 + lr) * K + half * K2 + lc;
    int nrow = n0 + lr;
    const float* Wp = Wcls;
    bool wvalid = true;
    if (nrow < NCLS)              Wp = Wcls + (size_t)nrow * K + half * K2 + lc;
    else if (nrow < NCLS + NREGR) Wp = Wreg + (size_t)(nrow - NCLS) * K + half * K2 + lc;
    else                          wvalid = false;
    float acc[4][4];
#pragma unroll
    for (int i = 0; i < 4; ++i)
#pragma unroll
        for (int j = 0; j < 4; ++j) acc[i][j] = 0.f;

    for (int k0 = 0; k0 < K2; k0 += 16) {
        float4 av = *(const float4*)(Ap + k0);
        float4 wv = wvalid ? *(const float4*)(Wp + k0) : make_float4(0.f, 0.f, 0.f, 0.f);
        As[half][lc + 0][lr] = av.x; As[half][lc + 1][lr] = av.y;
        As[half][lc + 2][lr] = av.z; As[half][lc + 3][lr] = av.w;
        Bs[half][lc + 0][lr] = wv.x; Bs[half][lc + 1][lr] = wv.y;
        Bs[half][lc + 2][lr] = wv.z; Bs[half][lc + 3][lr] = wv.w;
        __syncthreads();
#pragma unroll
        for (int kk = 0; kk < 16; ++kk) {
            float4 a = *(const float4*)&As[half][kk][tm << 2];
            float4 b = *(const float4*)&Bs[half][kk][tn << 2];
            float ar[4] = {a.x, a.y, a.z, a.w};
            float br[4] = {b.x, b.y, b.z, b.w};
#pragma unroll
            for (int i = 0; i < 4; ++i)
#pragma unroll
                for (int j = 0; j < 4; ++j)
                    acc[i][j] = fmaf(ar[i], br[j], acc[i][j]);
        }
        __syncthreads();
    }
    if (half == 1) {
#pragma unroll
        for (int i = 0; i < 4; ++i)
            *(float4*)&Pr[(tm << 2) + i][tn << 2] =
                make_float4(acc[i][0], acc[i][1], acc[i][2], acc[i][3]);
    }
    __syncthreads();
    if (half == 0) {
        float bb[4];
#pragma unroll
        for (int j = 0; j < 4; ++j) {
            int n = n0 + (tn << 2) + j;
            bb[j] = (n < NCLS) ? bcls[n] : ((n < NCLS + NREGR) ? breg[n - NCLS] : 0.f);
        }
#pragma unroll
        for (int i = 0; i < 4; ++i) {
            float4 p = *(const float4*)&Pr[(tm << 2) + i][tn << 2];
            float4 o;
            o.x = (acc[i][0] + p.x) + bb[0];
            o.y = (acc[i][1] + p.y) + bb[1];
            o.z = (acc[i][2] + p.z) + bb[2];
            o.w = (acc[i][3] + p.w) + bb[3];
            *(float4*)(C + (size_t)(m0 + (tm << 2) + i) * N2PAD + n0 + (tn << 2)) = o;
        }
    }
}

// ---------------- assemble proposals + scores + start/end + xsel ----------------
__global__ __launch_bounds__(256) void k_assemble(const float* __restrict__ C2,
                                                  const float* __restrict__ AD,
                                                  float* __restrict__ outP,
                                                  float* __restrict__ outS,
                                                  float* __restrict__ startv,
                                                  float* __restrict__ endv,
                                                  float* __restrict__ xsel)
{
    int mb = blockIdx.x;                 // 0..1343
    int b = mb / NEDGE, e = mb - b * NEDGE;
    const float* c2 = C2 + (size_t)mb * N2PAD;
    int tid = threadIdx.x;
    for (int idx = tid; idx < NANG * NPREDD; idx += 256) {
        int a = idx / NPREDD, p = idx - a * NPREDD;
        int prop = e * NANG + a;
        float v;
        if (p < 2) v = c2[a * 2 + p];
        else {
            v = AD[prop * NPREDD + p];
            if (p >= 4) v += c2[NCLS + a * 73 + (p - 4)];
        }
        outP[((size_t)b * NPROPP + prop) * NPREDD + p] = v;
    }
    if (tid < NANG) {
        int a = tid, prop = e * NANG + a;
        float c0 = c2[2 * a], c1 = c2[2 * a + 1];
        float mx = fmaxf(c0, c1);
        float e0 = expf(c0 - mx), e1 = expf(c1 - mx);
        outS[b * NPROPP + prop] = e1 / (e0 + e1);
        float p2 = AD[prop * NPREDD + 2];
        float p4 = AD[prop * NPREDD + 4] + c2[NCLS + a * 73];
        float st = fminf(fmaxf(rintf(p2 * NSTRIPSF), 0.0f), NSTRIPSF);  // round half-to-even
        float en = fminf(fmaxf(st + p4 - 1.0f, 0.0f), NSTRIPSF);
        startv[b * 720 + prop] = st;
        endv[b * 720 + prop] = en;
        int ksi = (int)st;
        // bit-identical to outP[..][5+ksi]
        xsel[b * 720 + prop] = AD[prop * NPREDD + 5 + ksi] + c2[NCLS + a * 73 + ksi + 1];
    }
}

// ---------------- per-batch stable descending rank sort ----------------
__global__ __launch_bounds__(256) void k_sort(const float* __restrict__ scores,
                                              int* __restrict__ order)
{
    int b = blockIdx.x, tid = threadIdx.x;
    __shared__ float s[NPROPP];
    for (int i = tid; i < NPROPP; i += 256) s[i] = scores[b * NPROPP + i];
    __syncthreads();
    for (int i = tid; i < NPROPP; i += 256) {
        float si = s[i];
        int r = 0;
        for (int j = 0; j < NPROPP; ++j) {
            float sj = s[j];
            r += (sj > si) || (sj == si && j < i);
        }
        order[b * 720 + r] = i;
    }
}

// ---------------- suppression matrix, 64x64 tiles, xsel fast path ----------------
__global__ __launch_bounds__(256) void k_supmat(const float* __restrict__ outP,
                                                const float* __restrict__ startv,
                                                const float* __restrict__ endv,
                                                const float* __restrict__ xsel,
                                                const int* __restrict__ order,
                                                u64* __restrict__ sup)
{
    int jt = blockIdx.x, it = blockIdx.y, b = blockIdx.z;
    int i0 = it * 64, j0 = jt * 64;
    int tid = threadIdx.x;
    if (j0 + 63 < i0) {                  // strictly below diagonal: zero words
        if (tid < 64) {
            int il = i0 + tid;
            if (il < NPROPP) sup[((size_t)b * NPROPP + il) * 12 + jt] = 0ull;
        }
        return;
    }
    __shared__ float SI[64], EI[64], XI[64];
    __shared__ float SJ[64], EJ[64], XJ[64];
    __shared__ int   OI[64], OJ[64];
    if (tid < 128) {
        int side = tid >> 6, q = tid & 63;
        int pos = (side ? j0 : i0) + q;
        int o = (pos < NPROPP) ? order[b * 720 + pos] : -1;
        float st = (o >= 0) ? startv[b * 720 + o] : 0.f;
        float en = (o >= 0) ? endv[b * 720 + o] : -2.f;   // cnt<=-1 -> never suppress
        float xv = (o >= 0) ? xsel[b * 720 + o] : 0.f;
        if (!side) { SI[q] = st; EI[q] = en; XI[q] = xv; OI[q] = o; }
        else       { SJ[q] = st; EJ[q] = en; XJ[q] = xv; OJ[q] = o; }
    }
    __syncthreads();
    int lane = tid & 63, w = tid >> 6;
    int j = j0 + lane;
    float sj = SJ[lane], ej = EJ[lane], xj = XJ[lane];
    const float* basexs = outP + (size_t)b * NPROPP * NPREDD + 5;
#pragma unroll 1
    for (int rep = 0; rep < 16; ++rep) {
        int iloc = w * 16 + rep;
        int il = i0 + iloc;
        float si = SI[iloc], ei = EI[iloc];
        float s = fmaxf(si, sj), e = fminf(ei, ej);
        float cnt = e - s + 1.0f;
        bool sp = false;
        if (cnt > 0.f) {
            if (e < s) {
                sp = true;                               // empty range: dist = 0
            } else {
                int ks = (int)s, ke = (int)e;
                if (si == sj && ke == ks) {
                    sp = (fabsf(XI[iloc] - xj) / fmaxf(cnt, 1.0f)) < 15.0f;
                } else {                                  // rare general case
                    const float* xi  = basexs + (size_t)OI[iloc] * NPREDD;
                    const float* xjp = basexs + (size_t)OJ[lane] * NPREDD;
                    float sum = 0.f;
                    for (int k = ks; k <= ke; ++k)
                        sum += fabsf(xi[k] - xjp[k]);
                    sp = (sum / fmaxf(cnt, 1.0f)) < 15.0f;
                }
            }
        }
        bool valid = (il < NPROPP) && (j < NPROPP) && (j > il);
        u64 msk = __ballot(valid && sp);
        if (lane == 0 && il < NPROPP)
            sup[((size_t)b * NPROPP + il) * 12 + jt] = msk;
    }
}

// ---------------- sequential NMS scan (per batch, 1 wave) ----------------
__global__ __launch_bounds__(64) void k_scan(const u64* __restrict__ sup,
                                             const int* __restrict__ order,
                                             float* __restrict__ keep_out)
{
    int b = blockIdx.x, lane = threadIdx.x;
    __shared__ float keepv[NPROPP];
    __shared__ int ord[NPROPP];
    for (int x = lane; x < NPROPP; x += 64) { keepv[x] = 0.f; ord[x] = order[b * 720 + x]; }
    __syncthreads();
    const u64* base = sup + (size_t)b * NPROPP * 12;

    u64 S[12];
#pragma unroll
    for (int t = 0; t < 12; ++t) S[t] = 0ull;

    u64 cur[12], nxt[12];
    {
        int r = lane;
#pragma unroll
        for (int t = 0; t < 12; ++t)
            cur[t] = (r < NPROPP) ? base[(size_t)r * 12 + t] : 0ull;
    }

    for (int c = 0; c < 12; ++c) {
        if (c < 11) {
            int r = (c + 1) * 64 + lane;
#pragma unroll
            for (int t = 0; t < 12; ++t) {
                int w = c + 1 + t;
                nxt[t] = (r < NPROPP && w < 12) ? base[(size_t)r * 12 + w] : 0ull;
            }
        }
        int imax = NPROPP - c * 64; if (imax > 64) imax = 64;
        u64 keepbits = 0ull;
        for (int ib = 0; ib < imax; ++ib) {
            bool keep = ((S[0] >> ib) & 1ull) == 0ull;   // uniform
            if (keep) {
                keepbits |= (1ull << ib);
#pragma unroll
                for (int t = 0; t < 12; ++t) {
                    unsigned rlo = (unsigned)__builtin_amdgcn_readlane((int)(unsigned)cur[t], ib);
                    unsigned rhi = (unsigned)__builtin_amdgcn_readlane((int)(cur[t] >> 32), ib);
                    S[t] |= ((u64)rhi << 32) | (u64)rlo;
                }
            }
        }
        if (lane < imax)
            keepv[ord[c * 64 + lane]] = ((keepbits >> lane) & 1ull) ? 1.f : 0.f;
#pragma unroll
        for (int t = 0; t < 11; ++t) S[t] = S[t + 1];
        S[11] = 0ull;
#pragma unroll
        for (int t = 0; t < 12; ++t) cur[t] = nxt[t];
    }
    __syncthreads();
    for (int x = lane; x < NPROPP; x += 64) keep_out[b * NPROPP + x] = keepv[x];
}

extern "C" void kernel_launch(void* const* d_in, const int* in_sizes, int n_in,
                              void* d_out, int out_size, void* d_ws, size_t ws_size,
                              hipStream_t stream)
{
    const float* feat  = (const float*)d_in[0];
    const float* Wconv = (const float*)d_in[1];
    const float* bconv = (const float*)d_in[2];
    const float* Wcls  = (const float*)d_in[3];
    const float* bcls  = (const float*)d_in[4];
    const float* Wreg  = (const float*)d_in[5];
    const float* breg  = (const float*)d_in[6];
    const float* AD    = (const float*)d_in[8];   // anchors_anchor_dim (714,77)

    float* out  = (float*)d_out;
    float* outP = out;                                     // proposals 32*714*77
    float* outK = out + (size_t)NB * NPROPP * NPREDD;      // keep mask  32*714
    float* outS = outK + (size_t)NB * NPROPP;              // scores     32*714

    float* ws = (float*)d_ws;
    float* A0 = ws;                   // [0, 688128)         dead after gemm1
    float* C1 = ws + 688128;          // [688128, 2064384)   dead after gemm2
    float* C2 = ws + 2064384;         // [2064384, 3784704)
    // reuse A0 region (dead by the time these are written):
    float* startv = ws;                                    // 32*720 floats
    float* endv   = ws + 23040;                            // 32*720 floats
    int*   order  = (int*)(ws + 46080);                    // 32*720 ints
    u64*   sup    = (u64*)(ws + 69120);                    // 32*714*12 u64, ends @617472
    float* xsel   = ws + 617472;                           // 32*720 floats, ends @640512

    k_gather  <<<dim3(2688),        dim3(256), 0, stream>>>(feat, A0);
    k_gemm1   <<<dim3(16, 21),      dim3(512), 0, stream>>>(A0, Wconv, bconv, C1);
    k_gemm2   <<<dim3(20, 21),      dim3(512), 0, stream>>>(C1, Wcls, bcls, Wreg, breg, C2);
    k_assemble<<<dim3(MTOT),        dim3(256), 0, stream>>>(C2, AD, outP, outS, startv, endv, xsel);
    k_sort    <<<dim3(NB),          dim3(256), 0, stream>>>(outS, order);
    k_supmat  <<<dim3(12, 12, NB),  dim3(256), 0, stream>>>(outP, startv, endv, xsel, order, sup);
    k_scan    <<<dim3(NB),          dim3(64),  0, stream>>>(sup, order, outK);
}

// Round 6
// 295.221 us; speedup vs baseline: 1.3431x; 1.0217x over previous
//
#include <hip/hip_runtime.h>
#include <math.h>

#define NB     32
#define FH     11
#define FW     20
#define CIN    512
#define CMID   1024
#define NANG   17
#define NPREDD 77
#define NEDGE  42
#define NPROPP 714
#define NOFF   72
#define NCLS   34
#define NREGR  1241
#define N2PAD  1280
#define MTOT   1344      // NB * NEDGE
#define NSTRIPSF 71.0f

typedef unsigned long long u64;

// ---------------- gather edge pixels: A0[m][c], m = b*42+e ----------------
__global__ __launch_bounds__(256) void k_gather(const float* __restrict__ feat,
                                                float* __restrict__ A0)
{
    int idx = blockIdx.x * 256 + threadIdx.x;    // exactly MTOT*CIN = 688128
    int m = idx >> 9, c = idx & 511;
    int b = m / NEDGE, e = m - b * NEDGE;
    int h, w;
    if (e < FH)          { h = e;      w = 0;      }
    else if (e < 2 * FH) { h = e - FH; w = FW - 1; }
    else                 { h = FH - 1; w = e - 2 * FH; }
    A0[idx] = feat[((size_t)(b * CIN + c) * FH + h) * FW + w];
}

// ---- GEMM1: C1[1344][1024] = A0[1344][512] * Wconv[1024][512]^T + b ----
// 1024 threads, 4-way K-split: quarter q (256 threads) accumulates
// k in [q*K/4, (q+1)*K/4) with the proven BK=16 single-buffer 64x64 loop.
// Tree reduction ((q0+q1)+q2)+q3 + bias via one LDS Pr buffer.
__global__ __launch_bounds__(1024) void k_gemm1(const float* __restrict__ A,
                                                const float* __restrict__ W,
                                                const float* __restrict__ bias,
                                                float* __restrict__ C)
{
    __shared__ __align__(16) float As[4][16][68];
    __shared__ __align__(16) float Bs[4][16][68];
    __shared__ __align__(16) float Pr[64][68];
    const int K = CIN, K4 = CIN / 4;
    int tid = threadIdx.x;
    int q = tid >> 8, t = tid & 255;
    int m0 = blockIdx.y * 64, n0 = blockIdx.x * 64;
    int tn = t & 15, tm = t >> 4;
    int lr = t >> 2, lc = (t & 3) << 2;
    const float* Ap = A + (size_t)(m0 + lr) * K + q * K4 + lc;
    const float* Wp = W + (size_t)(n0 + lr) * K + q * K4 + lc;
    float acc[4][4];
#pragma unroll
    for (int i = 0; i < 4; ++i)
#pragma unroll
        for (int j = 0; j < 4; ++j) acc[i][j] = 0.f;

    for (int k0 = 0; k0 < K4; k0 += 16) {
        float4 av = *(const float4*)(Ap + k0);
        float4 wv = *(const float4*)(Wp + k0);
        As[q][lc + 0][lr] = av.x; As[q][lc + 1][lr] = av.y;
        As[q][lc + 2][lr] = av.z; As[q][lc + 3][lr] = av.w;
        Bs[q][lc + 0][lr] = wv.x; Bs[q][lc + 1][lr] = wv.y;
        Bs[q][lc + 2][lr] = wv.z; Bs[q][lc + 3][lr] = wv.w;
        __syncthreads();
#pragma unroll
        for (int kk = 0; kk < 16; ++kk) {
            float4 a = *(const float4*)&As[q][kk][tm << 2];
            float4 b = *(const float4*)&Bs[q][kk][tn << 2];
            float ar[4] = {a.x, a.y, a.z, a.w};
            float br[4] = {b.x, b.y, b.z, b.w};
#pragma unroll
            for (int i = 0; i < 4; ++i)
#pragma unroll
                for (int j = 0; j < 4; ++j)
                    acc[i][j] = fmaf(ar[i], br[j], acc[i][j]);
        }
        __syncthreads();
    }
    // reduction: ((q0 + q1) + q2) + q3, then bias, q0 stores
#pragma unroll
    for (int src = 1; src <= 3; ++src) {
        if (q == src) {
#pragma unroll
            for (int i = 0; i < 4; ++i)
                *(float4*)&Pr[(tm << 2) + i][tn << 2] =
                    make_float4(acc[i][0], acc[i][1], acc[i][2], acc[i][3]);
        }
        __syncthreads();
        if (q == 0) {
#pragma unroll
            for (int i = 0; i < 4; ++i) {
                float4 p = *(const float4*)&Pr[(tm << 2) + i][tn << 2];
                acc[i][0] += p.x; acc[i][1] += p.y;
                acc[i][2] += p.z; acc[i][3] += p.w;
            }
        }
        __syncthreads();
    }
    if (q == 0) {
        float bb[4];
#pragma unroll
        for (int j = 0; j < 4; ++j) bb[j] = bias[n0 + (tn << 2) + j];
#pragma unroll
        for (int i = 0; i < 4; ++i) {
            float4 o;
            o.x = acc[i][0] + bb[0];
            o.y = acc[i][1] + bb[1];
            o.z = acc[i][2] + bb[2];
            o.w = acc[i][3] + bb[3];
            *(float4*)(C + (size_t)(m0 + (tm << 2) + i) * CMID + n0 + (tn << 2)) = o;
        }
    }
}

// ---- GEMM2: C2[1344][1280] = C1 * [Wcls;Wreg;0]^T + [bcls;breg;0] ----
__global__ __launch_bounds__(1024) void k_gemm2(const float* __restrict__ A,
                                                const float* __restrict__ Wcls,
                                                const float* __restrict__ bcls,
                                                const float* __restrict__ Wreg,
                                                const float* __restrict__ breg,
                                                float* __restrict__ C)
{
    __shared__ __align__(16) float As[4][16][68];
    __shared__ __align__(16) float Bs[4][16][68];
    __shared__ __align__(16) float Pr[64][68];
    const int K = CMID, K4 = CMID / 4;
    int tid = threadIdx.x;
    int q = tid >> 8, t = tid & 255;
    int m0 = blockIdx.y * 64, n0 = blockIdx.x * 64;
    int tn = t & 15, tm = t >> 4;
    int lr = t >> 2, lc = (t & 3) << 2;
    const float* Ap = A + (size_t)(m0 + lr) * K + q * K4 + lc;
    int nrow = n0 + lr;
    const float* Wp = Wcls;
    bool wvalid = true;
    if (nrow < NCLS)              Wp = Wcls + (size_t)nrow * K + q * K4 + lc;
    else if (nrow < NCLS + NREGR) Wp = Wreg + (size_t)(nrow - NCLS) * K + q * K4 + lc;
    else                          wvalid = false;
    float acc[4][4];
#pragma unroll
    for (int i = 0; i < 4; ++i)
#pragma unroll
        for (int j = 0; j < 4; ++j) acc[i][j] = 0.f;

    for (int k0 = 0; k0 < K4; k0 += 16) {
        float4 av = *(const float4*)(Ap + k0);
        float4 wv = wvalid ? *(const float4*)(Wp + k0) : make_float4(0.f, 0.f, 0.f, 0.f);
        As[q][lc + 0][lr] = av.x; As[q][lc + 1][lr] = av.y;
        As[q][lc + 2][lr] = av.z; As[q][lc + 3][lr] = av.w;
        Bs[q][lc + 0][lr] = wv.x; Bs[q][lc + 1][lr] = wv.y;
        Bs[q][lc + 2][lr] = wv.z; Bs[q][lc + 3][lr] = wv.w;
        __syncthreads();
#pragma unroll
        for (int kk = 0; kk < 16; ++kk) {
            float4 a = *(const float4*)&As[q][kk][tm << 2];
            float4 b = *(const float4*)&Bs[q][kk][tn << 2];
            float ar[4] = {a.x, a.y, a.z, a.w};
            float br[4] = {b.x, b.y, b.z, b.w};
#pragma unroll
            for (int i = 0; i < 4; ++i)
#pragma unroll
                for (int j = 0; j < 4; ++j)
                    acc[i][j] = fmaf(ar[i], br[j], acc[i][j]);
        }
        __syncthreads();
    }
#pragma unroll
    for (int src = 1; src <= 3; ++src) {
        if (q == src) {
#pragma unroll
            for (int i = 0; i < 4; ++i)
                *(float4*)&Pr[(tm << 2) + i][tn << 2] =
                    make_float4(acc[i][0], acc[i][1], acc[i][2], acc[i][3]);
        }
        __syncthreads();
        if (q == 0) {
#pragma unroll
            for (int i = 0; i < 4; ++i) {
                float4 p = *(const float4*)&Pr[(tm << 2) + i][tn << 2];
                acc[i][0] += p.x; acc[i][1] += p.y;
                acc[i][2] += p.z; acc[i][3] += p.w;
            }
        }
        __syncthreads();
    }
    if (q == 0) {
        float bb[4];
#pragma unroll
        for (int j = 0; j < 4; ++j) {
            int n = n0 + (tn << 2) + j;
            bb[j] = (n < NCLS) ? bcls[n] : ((n < NCLS + NREGR) ? breg[n - NCLS] : 0.f);
        }
#pragma unroll
        for (int i = 0; i < 4; ++i) {
            float4 o;
            o.x = acc[i][0] + bb[0];
            o.y = acc[i][1] + bb[1];
            o.z = acc[i][2] + bb[2];
            o.w = acc[i][3] + bb[3];
            *(float4*)(C + (size_t)(m0 + (tm << 2) + i) * N2PAD + n0 + (tn << 2)) = o;
        }
    }
}

// ---------------- assemble proposals + scores + start/end + xsel ----------------
__global__ __launch_bounds__(256) void k_assemble(const float* __restrict__ C2,
                                                  const float* __restrict__ AD,
                                                  float* __restrict__ outP,
                                                  float* __restrict__ outS,
                                                  float* __restrict__ startv,
                                                  float* __restrict__ endv,
                                                  float* __restrict__ xsel)
{
    int mb = blockIdx.x;                 // 0..1343
    int b = mb / NEDGE, e = mb - b * NEDGE;
    const float* c2 = C2 + (size_t)mb * N2PAD;
    int tid = threadIdx.x;
    for (int idx = tid; idx < NANG * NPREDD; idx += 256) {
        int a = idx / NPREDD, p = idx - a * NPREDD;
        int prop = e * NANG + a;
        float v;
        if (p < 2) v = c2[a * 2 + p];
        else {
            v = AD[prop * NPREDD + p];
            if (p >= 4) v += c2[NCLS + a * 73 + (p - 4)];
        }
        outP[((size_t)b * NPROPP + prop) * NPREDD + p] = v;
    }
    if (tid < NANG) {
        int a = tid, prop = e * NANG + a;
        float c0 = c2[2 * a], c1 = c2[2 * a + 1];
        float mx = fmaxf(c0, c1);
        float e0 = expf(c0 - mx), e1 = expf(c1 - mx);
        outS[b * NPROPP + prop] = e1 / (e0 + e1);
        float p2 = AD[prop * NPREDD + 2];
        float p4 = AD[prop * NPREDD + 4] + c2[NCLS + a * 73];
        float st = fminf(fmaxf(rintf(p2 * NSTRIPSF), 0.0f), NSTRIPSF);  // round half-to-even
        float en = fminf(fmaxf(st + p4 - 1.0f, 0.0f), NSTRIPSF);
        startv[b * 720 + prop] = st;
        endv[b * 720 + prop] = en;
        int ksi = (int)st;
        // bit-identical to outP[..][5+ksi]
        xsel[b * 720 + prop] = AD[prop * NPREDD + 5 + ksi] + c2[NCLS + a * 73 + ksi + 1];
    }
}

// ---------------- per-batch stable descending rank sort ----------------
__global__ __launch_bounds__(256) void k_sort(const float* __restrict__ scores,
                                              int* __restrict__ order)
{
    int b = blockIdx.x, tid = threadIdx.x;
    __shared__ float s[NPROPP];
    for (int i = tid; i < NPROPP; i += 256) s[i] = scores[b * NPROPP + i];
    __syncthreads();
    for (int i = tid; i < NPROPP; i += 256) {
        float si = s[i];
        int r = 0;
        for (int j = 0; j < NPROPP; ++j) {
            float sj = s[j];
            r += (sj > si) || (sj == si && j < i);
        }
        order[b * 720 + r] = i;
    }
}

// ---------------- suppression matrix, 64x64 tiles, xsel fast path ----------------
__global__ __launch_bounds__(256) void k_supmat(const float* __restrict__ outP,
                                                const float* __restrict__ startv,
                                                const float* __restrict__ endv,
                                                const float* __restrict__ xsel,
                                                const int* __restrict__ order,
                                                u64* __restrict__ sup)
{
    int jt = blockIdx.x, it = blockIdx.y, b = blockIdx.z;
    int i0 = it * 64, j0 = jt * 64;
    int tid = threadIdx.x;
    if (j0 + 63 < i0) {                  // strictly below diagonal: zero words
        if (tid < 64) {
            int il = i0 + tid;
            if (il < NPROPP) sup[((size_t)b * NPROPP + il) * 12 + jt] = 0ull;
        }
        return;
    }
    __shared__ float SI[64], EI[64], XI[64];
    __shared__ float SJ[64], EJ[64], XJ[64];
    __shared__ int   OI[64], OJ[64];
    if (tid < 128) {
        int side = tid >> 6, q = tid & 63;
        int pos = (side ? j0 : i0) + q;
        int o = (pos < NPROPP) ? order[b * 720 + pos] : -1;
        float st = (o >= 0) ? startv[b * 720 + o] : 0.f;
        float en = (o >= 0) ? endv[b * 720 + o] : -2.f;   // cnt<=-1 -> never suppress
        float xv = (o >= 0) ? xsel[b * 720 + o] : 0.f;
        if (!side) { SI[q] = st; EI[q] = en; XI[q] = xv; OI[q] = o; }
        else       { SJ[q] = st; EJ[q] = en; XJ[q] = xv; OJ[q] = o; }
    }
    __syncthreads();
    int lane = tid & 63, w = tid >> 6;
    int j = j0 + lane;
    float sj = SJ[lane], ej = EJ[lane], xj = XJ[lane];
    const float* basexs = outP + (size_t)b * NPROPP * NPREDD + 5;
#pragma unroll 1
    for (int rep = 0; rep < 16; ++rep) {
        int iloc = w * 16 + rep;
        int il = i0 + iloc;
        float si = SI[iloc], ei = EI[iloc];
        float s = fmaxf(si, sj), e = fminf(ei, ej);
        float cnt = e - s + 1.0f;
        bool sp = false;
        if (cnt > 0.f) {
            if (e < s) {
                sp = true;                               // empty range: dist = 0
            } else {
                int ks = (int)s, ke = (int)e;
                if (si == sj && ke == ks) {
                    sp = (fabsf(XI[iloc] - xj) / fmaxf(cnt, 1.0f)) < 15.0f;
                } else {                                  // rare general case
                    const float* xi  = basexs + (size_t)OI[iloc] * NPREDD;
                    const float* xjp = basexs + (size_t)OJ[lane] * NPREDD;
                    float sum = 0.f;
                    for (int k = ks; k <= ke; ++k)
                        sum += fabsf(xi[k] - xjp[k]);
                    sp = (sum / fmaxf(cnt, 1.0f)) < 15.0f;
                }
            }
        }
        bool valid = (il < NPROPP) && (j < NPROPP) && (j > il);
        u64 msk = __ballot(valid && sp);
        if (lane == 0 && il < NPROPP)
            sup[((size_t)b * NPROPP + il) * 12 + jt] = msk;
    }
}

// ---------------- sequential NMS scan (per batch, 1 wave) ----------------
__global__ __launch_bounds__(64) void k_scan(const u64* __restrict__ sup,
                                             const int* __restrict__ order,
                                             float* __restrict__ keep_out)
{
    int b = blockIdx.x, lane = threadIdx.x;
    __shared__ float keepv[NPROPP];
    __shared__ int ord[NPROPP];
    for (int x = lane; x < NPROPP; x += 64) { keepv[x] = 0.f; ord[x] = order[b * 720 + x]; }
    __syncthreads();
    const u64* base = sup + (size_t)b * NPROPP * 12;

    u64 S[12];
#pragma unroll
    for (int t = 0; t < 12; ++t) S[t] = 0ull;

    u64 cur[12], nxt[12];
    {
        int r = lane;
#pragma unroll
        for (int t = 0; t < 12; ++t)
            cur[t] = (r < NPROPP) ? base[(size_t)r * 12 + t] : 0ull;
    }

    for (int c = 0; c < 12; ++c) {
        if (c < 11) {
            int r = (c + 1) * 64 + lane;
#pragma unroll
            for (int t = 0; t < 12; ++t) {
                int w = c + 1 + t;
                nxt[t] = (r < NPROPP && w < 12) ? base[(size_t)r * 12 + w] : 0ull;
            }
        }
        int imax = NPROPP - c * 64; if (imax > 64) imax = 64;
        u64 keepbits = 0ull;
        for (int ib = 0; ib < imax; ++ib) {
            bool keep = ((S[0] >> ib) & 1ull) == 0ull;   // uniform
            if (keep) {
                keepbits |= (1ull << ib);
#pragma unroll
                for (int t = 0; t < 12; ++t) {
                    unsigned rlo = (unsigned)__builtin_amdgcn_readlane((int)(unsigned)cur[t], ib);
                    unsigned rhi = (unsigned)__builtin_amdgcn_readlane((int)(cur[t] >> 32), ib);
                    S[t] |= ((u64)rhi << 32) | (u64)rlo;
                }
            }
        }
        if (lane < imax)
            keepv[ord[c * 64 + lane]] = ((keepbits >> lane) & 1ull) ? 1.f : 0.f;
#pragma unroll
        for (int t = 0; t < 11; ++t) S[t] = S[t + 1];
        S[11] = 0ull;
#pragma unroll
        for (int t = 0; t < 12; ++t) cur[t] = nxt[t];
    }
    __syncthreads();
    for (int x = lane; x < NPROPP; x += 64) keep_out[b * NPROPP + x] = keepv[x];
}

extern "C" void kernel_launch(void* const* d_in, const int* in_sizes, int n_in,
                              void* d_out, int out_size, void* d_ws, size_t ws_size,
                              hipStream_t stream)
{
    const float* feat  = (const float*)d_in[0];
    const float* Wconv = (const float*)d_in[1];
    const float* bconv = (const float*)d_in[2];
    const float* Wcls  = (const float*)d_in[3];
    const float* bcls  = (const float*)d_in[4];
    const float* Wreg  = (const float*)d_in[5];
    const float* breg  = (const float*)d_in[6];
    const float* AD    = (const float*)d_in[8];   // anchors_anchor_dim (714,77)

    float* out  = (float*)d_out;
    float* outP = out;                                     // proposals 32*714*77
    float* outK = out + (size_t)NB * NPROPP * NPREDD;      // keep mask  32*714
    float* outS = outK + (size_t)NB * NPROPP;              // scores     32*714

    float* ws = (float*)d_ws;
    float* A0 = ws;                   // [0, 688128)         dead after gemm1
    float* C1 = ws + 688128;          // [688128, 2064384)   dead after gemm2
    float* C2 = ws + 2064384;         // [2064384, 3784704)
    // reuse A0 region (dead by the time these are written):
    float* startv = ws;                                    // 32*720 floats
    float* endv   = ws + 23040;                            // 32*720 floats
    int*   order  = (int*)(ws + 46080);                    // 32*720 ints
    u64*   sup    = (u64*)(ws + 69120);                    // 32*714*12 u64, ends @617472
    float* xsel   = ws + 617472;                           // 32*720 floats, ends @640512

    k_gather  <<<dim3(2688),        dim3(256),  0, stream>>>(feat, A0);
    k_gemm1   <<<dim3(16, 21),      dim3(1024), 0, stream>>>(A0, Wconv, bconv, C1);
    k_gemm2   <<<dim3(20, 21),      dim3(1024), 0, stream>>>(C1, Wcls, bcls, Wreg, breg, C2);
    k_assemble<<<dim3(MTOT),        dim3(256),  0, stream>>>(C2, AD, outP, outS, startv, endv, xsel);
    k_sort    <<<dim3(NB),          dim3(256),  0, stream>>>(outS, order);
    k_supmat  <<<dim3(12, 12, NB),  dim3(256),  0, stream>>>(outP, startv, endv, xsel, order, sup);
    k_scan    <<<dim3(NB),          dim3(64),   0, stream>>>(sup, order, outK);
}

// Round 7
// 260.641 us; speedup vs baseline: 1.5213x; 1.1327x over previous
//
#include <hip/hip_runtime.h>
#include <math.h>

#define NB     32
#define FH     11
#define FW     20
#define CIN    512
#define CMID   1024
#define NANG   17
#define NPREDD 77
#define NEDGE  42
#define NPROPP 714
#define NOFF   72
#define NCLS   34
#define NREGR  1241
#define N2PAD  1280
#define MTOT   1344      // NB * NEDGE
#define NSTRIPSF 71.0f
#define PADK   40        // padded LDS row length in bf16 units (conflict-free b128)

typedef unsigned long long u64;
typedef unsigned short ushortt;
typedef short s8v __attribute__((ext_vector_type(8)));
typedef float f4v __attribute__((ext_vector_type(4)));

__device__ inline ushortt f2bf(float f) {          // RNE fp32 -> bf16
    unsigned u = __float_as_uint(f);
    u += 0x7fffu + ((u >> 16) & 1u);
    return (ushortt)(u >> 16);
}
__device__ inline float bf2f(ushortt h) {
    return __uint_as_float(((unsigned)h) << 16);
}

// ------------- gather edge pixels + split to hi/lo bf16: A1[m][c] -------------
__global__ __launch_bounds__(256) void k_gather_split(const float* __restrict__ feat,
                                                      ushortt* __restrict__ Ahi,
                                                      ushortt* __restrict__ Alo)
{
    int idx = blockIdx.x * 256 + threadIdx.x;    // exactly MTOT*CIN = 688128
    int m = idx >> 9, c = idx & 511;
    int b = m / NEDGE, e = m - b * NEDGE;
    int h, w;
    if (e < FH)          { h = e;      w = 0;      }
    else if (e < 2 * FH) { h = e - FH; w = FW - 1; }
    else                 { h = FH - 1; w = e - 2 * FH; }
    float v = feat[((size_t)(b * CIN + c) * FH + h) * FW + w];
    ushortt hi = f2bf(v);
    Ahi[idx] = hi;
    Alo[idx] = f2bf(v - bf2f(hi));
}

// ------------- GEMM1 (MFMA): [1344][1024] = A1 x Wconv^T + bconv, out hi/lo bf16 ---
// 64x64 tile / 4 waves / wave 32x32 (2x2 16x16x32 frags). 4-term bf16 split:
// acc = hh + hl + lh + ll accumulated in fp32 MFMA regs, fixed order.
__global__ __launch_bounds__(256) void k_gemm1m(const ushortt* __restrict__ Ahi,
                                                const ushortt* __restrict__ Alo,
                                                const float* __restrict__ W,
                                                const float* __restrict__ bias,
                                                ushortt* __restrict__ Chi,
                                                ushortt* __restrict__ Clo)
{
    const int K = CIN, N = CMID;
    __shared__ __align__(16) ushortt Ash[64 * PADK], Asl[64 * PADK];
    __shared__ __align__(16) ushortt Bsh[64 * PADK], Bsl[64 * PADK];
    int tid = threadIdx.x;
    int m0 = blockIdx.y * 64, n0 = blockIdx.x * 64;
    int srow = tid >> 2, sg = tid & 3;
    int lane = tid & 63, wv = tid >> 6;
    int wm = (wv & 1) * 32, wn = (wv >> 1) * 32;
    int quad = lane >> 4, l15 = lane & 15;

    f4v acc[2][2];
#pragma unroll
    for (int i = 0; i < 2; ++i)
#pragma unroll
        for (int j = 0; j < 2; ++j) acc[i][j] = (f4v){0.f, 0.f, 0.f, 0.f};

    const ushortt* Ahp = Ahi + (size_t)(m0 + srow) * K + sg * 8;
    const ushortt* Alp = Alo + (size_t)(m0 + srow) * K + sg * 8;
    const float*   Wp  = W   + (size_t)(n0 + srow) * K + sg * 8;

    for (int k0 = 0; k0 < K; k0 += 32) {
        __syncthreads();
        s8v av = *(const s8v*)(Ahp + k0);
        s8v lv = *(const s8v*)(Alp + k0);
        float4 w0 = *(const float4*)(Wp + k0);
        float4 w1 = *(const float4*)(Wp + k0 + 4);
        float wf[8] = {w0.x, w0.y, w0.z, w0.w, w1.x, w1.y, w1.z, w1.w};
        s8v wh, wl;
#pragma unroll
        for (int j = 0; j < 8; ++j) {
            ushortt h = f2bf(wf[j]);
            wh[j] = (short)h;
            wl[j] = (short)f2bf(wf[j] - bf2f(h));
        }
        *(s8v*)&Ash[srow * PADK + sg * 8] = av;
        *(s8v*)&Asl[srow * PADK + sg * 8] = lv;
        *(s8v*)&Bsh[srow * PADK + sg * 8] = wh;
        *(s8v*)&Bsl[srow * PADK + sg * 8] = wl;
        __syncthreads();
        s8v ah[2], al[2], bh[2], bl[2];
#pragma unroll
        for (int s = 0; s < 2; ++s) {
            ah[s] = *(const s8v*)&Ash[(wm + s * 16 + l15) * PADK + quad * 8];
            al[s] = *(const s8v*)&Asl[(wm + s * 16 + l15) * PADK + quad * 8];
            bh[s] = *(const s8v*)&Bsh[(wn + s * 16 + l15) * PADK + quad * 8];
            bl[s] = *(const s8v*)&Bsl[(wn + s * 16 + l15) * PADK + quad * 8];
        }
#pragma unroll
        for (int sm = 0; sm < 2; ++sm)
#pragma unroll
            for (int sn = 0; sn < 2; ++sn) {
                acc[sm][sn] = __builtin_amdgcn_mfma_f32_16x16x32_bf16(al[sm], bl[sn], acc[sm][sn], 0, 0, 0);
                acc[sm][sn] = __builtin_amdgcn_mfma_f32_16x16x32_bf16(al[sm], bh[sn], acc[sm][sn], 0, 0, 0);
                acc[sm][sn] = __builtin_amdgcn_mfma_f32_16x16x32_bf16(ah[sm], bl[sn], acc[sm][sn], 0, 0, 0);
                acc[sm][sn] = __builtin_amdgcn_mfma_f32_16x16x32_bf16(ah[sm], bh[sn], acc[sm][sn], 0, 0, 0);
            }
    }
#pragma unroll
    for (int sm = 0; sm < 2; ++sm)
#pragma unroll
        for (int sn = 0; sn < 2; ++sn)
#pragma unroll
            for (int r = 0; r < 4; ++r) {
                int m = m0 + wm + sm * 16 + quad * 4 + r;
                int n = n0 + wn + sn * 16 + l15;
                float v = acc[sm][sn][r] + bias[n];
                ushortt h = f2bf(v);
                Chi[(size_t)m * N + n] = h;
                Clo[(size_t)m * N + n] = f2bf(v - bf2f(h));
            }
}

// ------------- GEMM2 (MFMA): C2[1344][1280] = A2 x [Wcls;Wreg;0]^T + bias, fp32 out ---
__global__ __launch_bounds__(256) void k_gemm2m(const ushortt* __restrict__ Ahi,
                                                const ushortt* __restrict__ Alo,
                                                const float* __restrict__ Wcls,
                                                const float* __restrict__ bcls,
                                                const float* __restrict__ Wreg,
                                                const float* __restrict__ breg,
                                                float* __restrict__ C)
{
    const int K = CMID;
    __shared__ __align__(16) ushortt Ash[64 * PADK], Asl[64 * PADK];
    __shared__ __align__(16) ushortt Bsh[64 * PADK], Bsl[64 * PADK];
    int tid = threadIdx.x;
    int m0 = blockIdx.y * 64, n0 = blockIdx.x * 64;
    int srow = tid >> 2, sg = tid & 3;
    int lane = tid & 63, wv = tid >> 6;
    int wm = (wv & 1) * 32, wn = (wv >> 1) * 32;
    int quad = lane >> 4, l15 = lane & 15;

    f4v acc[2][2];
#pragma unroll
    for (int i = 0; i < 2; ++i)
#pragma unroll
        for (int j = 0; j < 2; ++j) acc[i][j] = (f4v){0.f, 0.f, 0.f, 0.f};

    const ushortt* Ahp = Ahi + (size_t)(m0 + srow) * K + sg * 8;
    const ushortt* Alp = Alo + (size_t)(m0 + srow) * K + sg * 8;
    int nrow = n0 + srow;
    const float* Wp = Wcls;
    bool wvalid = true;
    if (nrow < NCLS)              Wp = Wcls + (size_t)nrow * K + sg * 8;
    else if (nrow < NCLS + NREGR) Wp = Wreg + (size_t)(nrow - NCLS) * K + sg * 8;
    else                          wvalid = false;

    for (int k0 = 0; k0 < K; k0 += 32) {
        __syncthreads();
        s8v av = *(const s8v*)(Ahp + k0);
        s8v lv = *(const s8v*)(Alp + k0);
        float4 w0, w1;
        if (wvalid) {
            w0 = *(const float4*)(Wp + k0);
            w1 = *(const float4*)(Wp + k0 + 4);
        } else {
            w0 = make_float4(0.f, 0.f, 0.f, 0.f);
            w1 = w0;
        }
        float wf[8] = {w0.x, w0.y, w0.z, w0.w, w1.x, w1.y, w1.z, w1.w};
        s8v wh, wl;
#pragma unroll
        for (int j = 0; j < 8; ++j) {
            ushortt h = f2bf(wf[j]);
            wh[j] = (short)h;
            wl[j] = (short)f2bf(wf[j] - bf2f(h));
        }
        *(s8v*)&Ash[srow * PADK + sg * 8] = av;
        *(s8v*)&Asl[srow * PADK + sg * 8] = lv;
        *(s8v*)&Bsh[srow * PADK + sg * 8] = wh;
        *(s8v*)&Bsl[srow * PADK + sg * 8] = wl;
        __syncthreads();
        s8v ah[2], al[2], bh[2], bl[2];
#pragma unroll
        for (int s = 0; s < 2; ++s) {
            ah[s] = *(const s8v*)&Ash[(wm + s * 16 + l15) * PADK + quad * 8];
            al[s] = *(const s8v*)&Asl[(wm + s * 16 + l15) * PADK + quad * 8];
            bh[s] = *(const s8v*)&Bsh[(wn + s * 16 + l15) * PADK + quad * 8];
            bl[s] = *(const s8v*)&Bsl[(wn + s * 16 + l15) * PADK + quad * 8];
        }
#pragma unroll
        for (int sm = 0; sm < 2; ++sm)
#pragma unroll
            for (int sn = 0; sn < 2; ++sn) {
                acc[sm][sn] = __builtin_amdgcn_mfma_f32_16x16x32_bf16(al[sm], bl[sn], acc[sm][sn], 0, 0, 0);
                acc[sm][sn] = __builtin_amdgcn_mfma_f32_16x16x32_bf16(al[sm], bh[sn], acc[sm][sn], 0, 0, 0);
                acc[sm][sn] = __builtin_amdgcn_mfma_f32_16x16x32_bf16(ah[sm], bl[sn], acc[sm][sn], 0, 0, 0);
                acc[sm][sn] = __builtin_amdgcn_mfma_f32_16x16x32_bf16(ah[sm], bh[sn], acc[sm][sn], 0, 0, 0);
            }
    }
#pragma unroll
    for (int sm = 0; sm < 2; ++sm)
#pragma unroll
        for (int sn = 0; sn < 2; ++sn)
#pragma unroll
            for (int r = 0; r < 4; ++r) {
                int m = m0 + wm + sm * 16 + quad * 4 + r;
                int n = n0 + wn + sn * 16 + l15;
                float bb = (n < NCLS) ? bcls[n] : ((n < NCLS + NREGR) ? breg[n - NCLS] : 0.f);
                C[(size_t)m * N2PAD + n] = acc[sm][sn][r] + bb;
            }
}

// ---------------- assemble proposals + scores + start/end + xsel ----------------
__global__ __launch_bounds__(256) void k_assemble(const float* __restrict__ C2,
                                                  const float* __restrict__ AD,
                                                  float* __restrict__ outP,
                                                  float* __restrict__ outS,
                                                  float* __restrict__ startv,
                                                  float* __restrict__ endv,
                                                  float* __restrict__ xsel)
{
    int mb = blockIdx.x;                 // 0..1343
    int b = mb / NEDGE, e = mb - b * NEDGE;
    const float* c2 = C2 + (size_t)mb * N2PAD;
    int tid = threadIdx.x;
    for (int idx = tid; idx < NANG * NPREDD; idx += 256) {
        int a = idx / NPREDD, p = idx - a * NPREDD;
        int prop = e * NANG + a;
        float v;
        if (p < 2) v = c2[a * 2 + p];
        else {
            v = AD[prop * NPREDD + p];
            if (p >= 4) v += c2[NCLS + a * 73 + (p - 4)];
        }
        outP[((size_t)b * NPROPP + prop) * NPREDD + p] = v;
    }
    if (tid < NANG) {
        int a = tid, prop = e * NANG + a;
        float c0 = c2[2 * a], c1 = c2[2 * a + 1];
        float mx = fmaxf(c0, c1);
        float e0 = expf(c0 - mx), e1 = expf(c1 - mx);
        outS[b * NPROPP + prop] = e1 / (e0 + e1);
        float p2 = AD[prop * NPREDD + 2];
        float p4 = AD[prop * NPREDD + 4] + c2[NCLS + a * 73];
        float st = fminf(fmaxf(rintf(p2 * NSTRIPSF), 0.0f), NSTRIPSF);  // round half-to-even
        float en = fminf(fmaxf(st + p4 - 1.0f, 0.0f), NSTRIPSF);
        startv[b * 720 + prop] = st;
        endv[b * 720 + prop] = en;
        int ksi = (int)st;
        // bit-identical to outP[..][5+ksi]
        xsel[b * 720 + prop] = AD[prop * NPREDD + 5 + ksi] + c2[NCLS + a * 73 + ksi + 1];
    }
}

// ---------------- per-batch stable descending rank sort ----------------
__global__ __launch_bounds__(256) void k_sort(const float* __restrict__ scores,
                                              int* __restrict__ order)
{
    int b = blockIdx.x, tid = threadIdx.x;
    __shared__ float s[NPROPP];
    for (int i = tid; i < NPROPP; i += 256) s[i] = scores[b * NPROPP + i];
    __syncthreads();
    for (int i = tid; i < NPROPP; i += 256) {
        float si = s[i];
        int r = 0;
        for (int j = 0; j < NPROPP; ++j) {
            float sj = s[j];
            r += (sj > si) || (sj == si && j < i);
        }
        order[b * 720 + r] = i;
    }
}

// ---------------- suppression matrix, 64x64 tiles, xsel fast path ----------------
__global__ __launch_bounds__(256) void k_supmat(const float* __restrict__ outP,
                                                const float* __restrict__ startv,
                                                const float* __restrict__ endv,
                                                const float* __restrict__ xsel,
                                                const int* __restrict__ order,
                                                u64* __restrict__ sup)
{
    int jt = blockIdx.x, it = blockIdx.y, b = blockIdx.z;
    int i0 = it * 64, j0 = jt * 64;
    int tid = threadIdx.x;
    if (j0 + 63 < i0) {                  // strictly below diagonal: zero words
        if (tid < 64) {
            int il = i0 + tid;
            if (il < NPROPP) sup[((size_t)b * NPROPP + il) * 12 + jt] = 0ull;
        }
        return;
    }
    __shared__ float SI[64], EI[64], XI[64];
    __shared__ float SJ[64], EJ[64], XJ[64];
    __shared__ int   OI[64], OJ[64];
    if (tid < 128) {
        int side = tid >> 6, q = tid & 63;
        int pos = (side ? j0 : i0) + q;
        int o = (pos < NPROPP) ? order[b * 720 + pos] : -1;
        float st = (o >= 0) ? startv[b * 720 + o] : 0.f;
        float en = (o >= 0) ? endv[b * 720 + o] : -2.f;   // cnt<=-1 -> never suppress
        float xv = (o >= 0) ? xsel[b * 720 + o] : 0.f;
        if (!side) { SI[q] = st; EI[q] = en; XI[q] = xv; OI[q] = o; }
        else       { SJ[q] = st; EJ[q] = en; XJ[q] = xv; OJ[q] = o; }
    }
    __syncthreads();
    int lane = tid & 63, w = tid >> 6;
    int j = j0 + lane;
    float sj = SJ[lane], ej = EJ[lane], xj = XJ[lane];
    const float* basexs = outP + (size_t)b * NPROPP * NPREDD + 5;
#pragma unroll 1
    for (int rep = 0; rep < 16; ++rep) {
        int iloc = w * 16 + rep;
        int il = i0 + iloc;
        float si = SI[iloc], ei = EI[iloc];
        float s = fmaxf(si, sj), e = fminf(ei, ej);
        float cnt = e - s + 1.0f;
        bool sp = false;
        if (cnt > 0.f) {
            if (e < s) {
                sp = true;                               // empty range: dist = 0
            } else {
                int ks = (int)s, ke = (int)e;
                if (si == sj && ke == ks) {
                    sp = (fabsf(XI[iloc] - xj) / fmaxf(cnt, 1.0f)) < 15.0f;
                } else {                                  // rare general case
                    const float* xi  = basexs + (size_t)OI[iloc] * NPREDD;
                    const float* xjp = basexs + (size_t)OJ[lane] * NPREDD;
                    float sum = 0.f;
                    for (int k = ks; k <= ke; ++k)
                        sum += fabsf(xi[k] - xjp[k]);
                    sp = (sum / fmaxf(cnt, 1.0f)) < 15.0f;
                }
            }
        }
        bool valid = (il < NPROPP) && (j < NPROPP) && (j > il);
        u64 msk = __ballot(valid && sp);
        if (lane == 0 && il < NPROPP)
            sup[((size_t)b * NPROPP + il) * 12 + jt] = msk;
    }
}

// ---------------- sequential NMS scan (per batch, 1 wave) ----------------
__global__ __launch_bounds__(64) void k_scan(const u64* __restrict__ sup,
                                             const int* __restrict__ order,
                                             float* __restrict__ keep_out)
{
    int b = blockIdx.x, lane = threadIdx.x;
    __shared__ float keepv[NPROPP];
    __shared__ int ord[NPROPP];
    for (int x = lane; x < NPROPP; x += 64) { keepv[x] = 0.f; ord[x] = order[b * 720 + x]; }
    __syncthreads();
    const u64* base = sup + (size_t)b * NPROPP * 12;

    u64 S[12];
#pragma unroll
    for (int t = 0; t < 12; ++t) S[t] = 0ull;

    u64 cur[12], nxt[12];
    {
        int r = lane;
#pragma unroll
        for (int t = 0; t < 12; ++t)
            cur[t] = (r < NPROPP) ? base[(size_t)r * 12 + t] : 0ull;
    }

    for (int c = 0; c < 12; ++c) {
        if (c < 11) {
            int r = (c + 1) * 64 + lane;
#pragma unroll
            for (int t = 0; t < 12; ++t) {
                int w = c + 1 + t;
                nxt[t] = (r < NPROPP && w < 12) ? base[(size_t)r * 12 + w] : 0ull;
            }
        }
        int imax = NPROPP - c * 64; if (imax > 64) imax = 64;
        u64 keepbits = 0ull;
        for (int ib = 0; ib < imax; ++ib) {
            bool keep = ((S[0] >> ib) & 1ull) == 0ull;   // uniform
            if (keep) {
                keepbits |= (1ull << ib);
#pragma unroll
                for (int t = 0; t < 12; ++t) {
                    unsigned rlo = (unsigned)__builtin_amdgcn_readlane((int)(unsigned)cur[t], ib);
                    unsigned rhi = (unsigned)__builtin_amdgcn_readlane((int)(cur[t] >> 32), ib);
                    S[t] |= ((u64)rhi << 32) | (u64)rlo;
                }
            }
        }
        if (lane < imax)
            keepv[ord[c * 64 + lane]] = ((keepbits >> lane) & 1ull) ? 1.f : 0.f;
#pragma unroll
        for (int t = 0; t < 11; ++t) S[t] = S[t + 1];
        S[11] = 0ull;
#pragma unroll
        for (int t = 0; t < 12; ++t) cur[t] = nxt[t];
    }
    __syncthreads();
    for (int x = lane; x < NPROPP; x += 64) keep_out[b * NPROPP + x] = keepv[x];
}

extern "C" void kernel_launch(void* const* d_in, const int* in_sizes, int n_in,
                              void* d_out, int out_size, void* d_ws, size_t ws_size,
                              hipStream_t stream)
{
    const float* feat  = (const float*)d_in[0];
    const float* Wconv = (const float*)d_in[1];
    const float* bconv = (const float*)d_in[2];
    const float* Wcls  = (const float*)d_in[3];
    const float* bcls  = (const float*)d_in[4];
    const float* Wreg  = (const float*)d_in[5];
    const float* breg  = (const float*)d_in[6];
    const float* AD    = (const float*)d_in[8];   // anchors_anchor_dim (714,77)

    float* out  = (float*)d_out;
    float* outP = out;                                     // proposals 32*714*77
    float* outK = out + (size_t)NB * NPROPP * NPREDD;      // keep mask  32*714
    float* outS = outK + (size_t)NB * NPROPP;              // scores     32*714

    float* ws = (float*)d_ws;
    // [0, 688128) floats: A1hi/A1lo bf16 (dead after gemm1) -> NMS scratch later
    ushortt* A1hi = (ushortt*)ws;                          // 688128 bf16
    ushortt* A1lo = (ushortt*)(ws + 344064);               // 688128 bf16
    ushortt* A2hi = (ushortt*)(ws + 688128);               // 1344*1024 bf16
    ushortt* A2lo = (ushortt*)(ws + 1376256);              // 1344*1024 bf16
    float*   C2   = ws + 2064384;                          // 1344*1280 fp32, ends 3784704
    // NMS scratch overlays dead A1 region:
    float* startv = ws;                                    // 32*720 floats
    float* endv   = ws + 23040;                            // 32*720 floats
    int*   order  = (int*)(ws + 46080);                    // 32*720 ints
    u64*   sup    = (u64*)(ws + 69120);                    // 32*714*12 u64, ends @617472
    float* xsel   = ws + 617472;                           // 32*720 floats, ends @640512

    k_gather_split<<<dim3(2688),       dim3(256), 0, stream>>>(feat, A1hi, A1lo);
    k_gemm1m      <<<dim3(16, 21),     dim3(256), 0, stream>>>(A1hi, A1lo, Wconv, bconv, A2hi, A2lo);
    k_gemm2m      <<<dim3(20, 21),     dim3(256), 0, stream>>>(A2hi, A2lo, Wcls, bcls, Wreg, breg, C2);
    k_assemble    <<<dim3(MTOT),       dim3(256), 0, stream>>>(C2, AD, outP, outS, startv, endv, xsel);
    k_sort        <<<dim3(NB),         dim3(256), 0, stream>>>(outS, order);
    k_supmat      <<<dim3(12, 12, NB), dim3(256), 0, stream>>>(outP, startv, endv, xsel, order, sup);
    k_scan        <<<dim3(NB),         dim3(64),  0, stream>>>(sup, order, outK);
}